// Round 17
// baseline (133.649 us; speedup 1.0000x reference)
//
#include <hip/hip_runtime.h>
#include <hip/hip_bf16.h>

typedef __attribute__((ext_vector_type(8))) short short8;
typedef __attribute__((ext_vector_type(4))) float f32x4;
typedef __attribute__((ext_vector_type(4))) float float4v;
typedef __attribute__((ext_vector_type(4))) unsigned short ushort4v;
typedef __attribute__((ext_vector_type(4))) unsigned int uint4v;

#define MFMA16(a, b, c) __builtin_amdgcn_mfma_f32_16x16x32_bf16((a), (b), (c), 0, 0, 0)

__device__ __forceinline__ unsigned short f2bf(float f) {
    union { float f; unsigned u; } v; v.f = f;
    unsigned r = v.u + 0x7fffu + ((v.u >> 16) & 1u);
    return (unsigned short)(r >> 16);
}
__device__ __forceinline__ float bf2f(unsigned short h) {
    union { unsigned u; float f; } v; v.u = (unsigned)h << 16;
    return v.f;
}
__device__ __forceinline__ float asf(unsigned u) {
    union { unsigned u; float f; } v; v.u = u;
    return v.f;
}
__device__ __forceinline__ unsigned cvt_pk_bf16(float lo, float hi) {
    unsigned r;
    asm("v_cvt_pk_bf16_f32 %0, %1, %2" : "=v"(r) : "v"(lo), "v"(hi));
    return r;
}
// async global->LDS, 16B per lane. LDS dest = wave-uniform base + lane*16.
__device__ __forceinline__ void gl16(const void* g, void* l) {
    __builtin_amdgcn_global_load_lds(
        (const __attribute__((address_space(1))) unsigned int*)g,
        (__attribute__((address_space(3))) unsigned int*)l, 16, 0, 0);
}

// ---------------------------------------------------------------------------
// Kernel 1: weights 512x512 fp32 -> bf16 transposed, PRE-SWIZZLED rows
// (chunk c of row n stored at c^(n&7)).
// ---------------------------------------------------------------------------
__global__ __launch_bounds__(256) void wtrans_kernel(
    const float* __restrict__ W0, const float* __restrict__ W1,
    const float* __restrict__ W2, const float* __restrict__ W3,
    unsigned short* __restrict__ T0, unsigned short* __restrict__ T1,
    unsigned short* __restrict__ T2, unsigned short* __restrict__ T3)
{
    const int z = blockIdx.z;
    const float* W = (z == 0) ? W0 : (z == 1) ? W1 : (z == 2) ? W2 : W3;
    unsigned short* T = (z == 0) ? T0 : (z == 1) ? T1 : (z == 2) ? T2 : T3;

    __shared__ unsigned short tile[64][72];
    const int k0 = blockIdx.x * 64, n0 = blockIdx.y * 64;
    const int t = threadIdx.x;

#pragma unroll
    for (int p = 0; p < 4; ++p) {
        int idx = p * 256 + t;
        int k = idx >> 4, c4 = idx & 15;
        float4v v = *(const float4v*)(W + (size_t)(k0 + k) * 512 + n0 + c4 * 4);
#pragma unroll
        for (int j = 0; j < 4; ++j) tile[k][c4 * 4 + j] = f2bf(v[j]);
    }
    __syncthreads();
#pragma unroll
    for (int p = 0; p < 2; ++p) {
        int idx = p * 256 + t;
        int n = idx >> 3, c = idx & 7;
        short8 o;
#pragma unroll
        for (int j = 0; j < 8; ++j) o[j] = (short)tile[c * 8 + j][n];
        *(short8*)(T + (size_t)(n0 + n) * 512 + k0 + ((c ^ (n & 7)) * 8)) = o;
    }
}

// ---------------------------------------------------------------------------
// Kernel 2: q/k/v projection GEMM. 512 threads = 8 waves, TILE 128x128,
// BK=64, wave tile 64x32 (acc 32 VGPR). LDS 48KB (A fp32 32 + B 16) ->
// 3 blocks/CU x 8 waves = 24 waves/CU (wave-count law: R8/R9/R14).
// A staged raw fp32 via gl16 (pre-swizzled source, converted bf16 on read) --
// R12/R14-proven path, bit-identical. B staged via gl16 from pre-swizzled WT.
// No launch bound (R10/R11 lessons). XCD-aware grid 1536: 12 (col,z) combos
// of one 128-row block per XCD.
// Epilogues: z==0 -> qb plain; z==1 -> kb key-row-permuted (kappa^-1) +
// col-swizzled; z==2 -> vT transposed + pre-swizzled key-chunks.
// ---------------------------------------------------------------------------
__global__ __launch_bounds__(512) void proj_kernel(
    const float* __restrict__ Q, const float* __restrict__ Kin,
    const unsigned short* __restrict__ WqT, const unsigned short* __restrict__ WkT,
    const unsigned short* __restrict__ WvT,
    const float* __restrict__ bq, const float* __restrict__ bk, const float* __restrict__ bv,
    unsigned short* __restrict__ qb, unsigned short* __restrict__ kb,
    unsigned short* __restrict__ vT)
{
    const int bid = blockIdx.x;
    const int xcd = bid & 7, idx = bid >> 3;        // idx in [0,192)
    const int q12 = idx / 12, combo = idx - q12 * 12;
    const int z = combo >> 2;
    const int rowbase = (xcd + 8 * q12) * 128;
    const int colbase = (combo & 3) * 128;

    const float* A = (z == 0) ? Q : Kin;
    const unsigned short* WT = (z == 0) ? WqT : (z == 1) ? WkT : WvT;
    const float* bias = (z == 0) ? bq : (z == 1) ? bk : bv;

    __shared__ float Alf[128 * 64];            // 32 KB fp32, chunk-swizzled
    __shared__ unsigned short Bl[128 * 64];    // 16 KB bf16

    const int t = threadIdx.x;                 // 0..511
    const int lane = t & 63, wid = t >> 6;     // wid 0..7
    const int wm = wid >> 2, wn = wid & 3;     // wave grid 2x4, tile 64x32
    const int l15 = lane & 15, grp = lane >> 4;

    f32x4 acc[4][2];
#pragma unroll
    for (int i = 0; i < 4; ++i)
#pragma unroll
        for (int j = 0; j < 2; ++j) acc[i][j] = (f32x4){0.f, 0.f, 0.f, 0.f};

    for (int kt = 0; kt < 8; ++kt) {
        // B: 128 rows x 8 chunks, 2 gl16/thread, linear dest
#pragma unroll
        for (int j = 0; j < 2; ++j) {
            int n = wid * 16 + j * 8 + (lane >> 3);
            gl16(WT + (size_t)(colbase + n) * 512 + kt * 64 + (lane & 7) * 8,
                 &Bl[wid * 1024 + j * 512]);
        }
        // A: 128 rows x 16 chunks fp32, 4 gl16/thread, source pre-swizzled
#pragma unroll
        for (int i = 0; i < 4; ++i) {
            int r = wid * 16 + i * 4 + (lane >> 4);
            int cdst = lane & 15;
            gl16(A + (size_t)(rowbase + r) * 512 + kt * 64 + ((cdst ^ (r & 15)) << 2),
                 &Alf[wid * 1024 + i * 256]);
        }
        __syncthreads();
#pragma unroll
        for (int kk = 0; kk < 2; ++kk) {
            short8 af[4], bfr[2];
#pragma unroll
            for (int m = 0; m < 4; ++m) {
                int r = wm * 64 + m * 16 + l15;
                int c0 = kk * 8 + grp * 2;
                const char* base = (const char*)Alf + r * 256;
                float4v f0 = *(const float4v*)(base + ((c0 ^ (r & 15)) << 4));
                float4v f1 = *(const float4v*)(base + (((c0 + 1) ^ (r & 15)) << 4));
                union { uint4v u; short8 s8; } cv;
                cv.u[0] = cvt_pk_bf16(f0[0], f0[1]);
                cv.u[1] = cvt_pk_bf16(f0[2], f0[3]);
                cv.u[2] = cvt_pk_bf16(f1[0], f1[1]);
                cv.u[3] = cvt_pk_bf16(f1[2], f1[3]);
                af[m] = cv.s8;
            }
#pragma unroll
            for (int n = 0; n < 2; ++n) {
                int r = wn * 32 + n * 16 + l15;
                bfr[n] = *(const short8*)((const char*)Bl + r * 128 + (((kk * 4 + grp) ^ (r & 7)) << 4));
            }
#pragma unroll
            for (int m = 0; m < 4; ++m)
#pragma unroll
                for (int n = 0; n < 2; ++n)
                    acc[m][n] = MFMA16(af[m], bfr[n], acc[m][n]);
        }
        __syncthreads();
    }

    if (z == 2) {
        // v epilogue: write vT[(b*8+h)*64+d][key] transposed + pre-swizzled
#pragma unroll
        for (int n = 0; n < 2; ++n) {
            int col = colbase + wn * 32 + n * 16 + l15;
            float bvv = bias[col];
            int h_ = col >> 6, d_ = col & 63;
#pragma unroll
            for (int m = 0; m < 4; ++m) {
                int row0 = rowbase + wm * 64 + m * 16 + grp * 4;
                int b_ = row0 >> 10;
                int key0 = row0 & 1023;
                int keypos = (key0 & ~63) + ((((key0 >> 3) & 7) ^ (d_ & 7)) << 3) + (key0 & 7);
                ushort4v w;
#pragma unroll
                for (int r = 0; r < 4; ++r) w[r] = f2bf(acc[m][n][r] + bvv);
                *(ushort4v*)(vT + ((size_t)(b_ * 8 + h_) * 64 + d_) * 1024 + keypos) = w;
            }
        }
    } else if (z == 1) {
        // k epilogue: row-permute within 64-blocks (kappa^-1) + col swizzle by
        // stored row. kappa^-1(k): y = [k2, k5, k4, k3, k1, k0]
#pragma unroll
        for (int n = 0; n < 2; ++n) {
            int col = colbase + wn * 32 + n * 16 + l15;
            float bvv = bias[col];
#pragma unroll
            for (int m = 0; m < 4; ++m) {
                int row0 = rowbase + wm * 64 + m * 16 + grp * 4;
#pragma unroll
                for (int r = 0; r < 4; ++r) {
                    int row = row0 + r;
                    int k6 = row & 63;
                    int y = ((k6 & 4) << 3) | ((k6 & 56) >> 1) | (k6 & 3);
                    int Y = (row & ~63) | y;
                    int colp = col ^ ((y & 7) << 3);
                    kb[(size_t)Y * 512 + colp] = f2bf(acc[m][n][r] + bvv);
                }
            }
        }
    } else {
#pragma unroll
        for (int n = 0; n < 2; ++n) {
            int col = colbase + wn * 32 + n * 16 + l15;
            float bvv = bias[col];
#pragma unroll
            for (int m = 0; m < 4; ++m) {
                int row0 = rowbase + wm * 64 + m * 16 + grp * 4;
#pragma unroll
                for (int r = 0; r < 4; ++r)
                    qb[(size_t)(row0 + r) * 512 + col] = f2bf(acc[m][n][r] + bvv);
            }
        }
    }
}

// ---------------------------------------------------------------------------
// Kernel 3: flash attention (R5 structure + register-level wins). 256 threads
// = 4 waves x 32 q, Qwg=128, grid 1024. K/V double-buffered in 32KB LDS via
// gl16; one __syncthreads per iter (skipped on the final iter). P fully
// in-register via kb's key-row permutation; q pre-scaled by C.
// ---------------------------------------------------------------------------
__global__ __launch_bounds__(256, 4) void attn_kernel(
    const unsigned short* __restrict__ qb, const unsigned short* __restrict__ kbs,
    const unsigned short* __restrict__ vTs, unsigned short* __restrict__ Opre)
{
    __shared__ unsigned short Kl[2][64 * 64];   // [key'][kd] swizzled, row-permuted
    __shared__ unsigned short Vl[2][64 * 64];   // [d][key] swizzled

    const int t = threadIdx.x, lane = t & 63, wid = t >> 6;
    const int l15 = lane & 15, grp = lane >> 4;

    // XCD-aware decode: bid&7 = h; qt-siblings of one (b,h) adjacent.
    const int bid = blockIdx.x;
    const int h = bid & 7, r2 = bid >> 3;
    const int b = r2 >> 3, qt = r2 & 7;
    const int qbase = qt * 128 + wid * 32;

    // staging source addrs (per-lane); dest = wave-uniform base + lane*16
    const unsigned short* ksrc = kbs + (size_t)(b * 1024 + (t >> 3)) * 512 + h * 64 + (t & 7) * 8;
    const unsigned short* vsrc = vTs + ((size_t)(b * 8 + h) * 64 + (t >> 3)) * 1024 + (t & 7) * 8;

#define STAGE(bsel, tile) do { \
    gl16(ksrc + (size_t)((tile) * 64) * 512,      &Kl[bsel][wid * 512]); \
    gl16(ksrc + (size_t)((tile) * 64 + 32) * 512, &Kl[bsel][2048 + wid * 512]); \
    gl16(vsrc + (tile) * 64,                      &Vl[bsel][wid * 512]); \
    gl16(vsrc + 32768 + (tile) * 64,              &Vl[bsel][2048 + wid * 512]); } while (0)

    const float C = 0.06375871f;  // (1/sqrt(512)) * log2(e)

    // Q as B-frags
    short8 qfrag[2][2];
#pragma unroll
    for (int qf = 0; qf < 2; ++qf)
#pragma unroll
        for (int kk = 0; kk < 2; ++kk)
            qfrag[qf][kk] = *(const short8*)(
                qb + (size_t)(b * 1024 + qbase + qf * 16 + l15) * 512 + h * 64 + kk * 32 + grp * 8);

    STAGE(0, 0);

    // pre-scale q by C in registers (one-time): s from MFMA comes pre-scaled
#pragma unroll
    for (int qf = 0; qf < 2; ++qf)
#pragma unroll
        for (int kk = 0; kk < 2; ++kk) {
            union { short8 s; uint4v u; } io;
            io.s = qfrag[qf][kk];
#pragma unroll
            for (int j = 0; j < 4; ++j) {
                unsigned w = io.u[j];
                float flo = asf(w << 16) * C;
                float fhi = asf(w & 0xffff0000u) * C;
                io.u[j] = cvt_pk_bf16(flo, fhi);
            }
            qfrag[qf][kk] = io.s;
        }

    f32x4 o[2][4];
#pragma unroll
    for (int qf = 0; qf < 2; ++qf)
#pragma unroll
        for (int df = 0; df < 4; ++df) o[qf][df] = (f32x4){0.f, 0.f, 0.f, 0.f};
    float mrun[2] = {0.f, 0.f}, lrun[2] = {0.f, 0.f};

    __syncthreads();

    for (int kt = 0; kt < 16; ++kt) {
        const int buf = kt & 1;
        if (kt < 15) STAGE(buf ^ 1, kt + 1);   // flies during compute

        const char* Kb_ = (const char*)&Kl[buf][0];
        const char* Vb_ = (const char*)&Vl[buf][0];

        // S^T rows rho = nf*16+grp*4+r (key kappa(rho)), col q = l15; PRE-SCALED
        f32x4 s[2][4];
#pragma unroll
        for (int qf = 0; qf < 2; ++qf)
#pragma unroll
            for (int nf = 0; nf < 4; ++nf) s[qf][nf] = (f32x4){0.f, 0.f, 0.f, 0.f};
        __builtin_amdgcn_s_setprio(1);
#pragma unroll
        for (int kk = 0; kk < 2; ++kk) {
            short8 kf[4];
#pragma unroll
            for (int nf = 0; nf < 4; ++nf) {
                int r = nf * 16 + l15;
                kf[nf] = *(const short8*)(Kb_ + r * 128 + (((kk * 4 + grp) ^ (r & 7)) << 4));
            }
#pragma unroll
            for (int qf = 0; qf < 2; ++qf)
#pragma unroll
                for (int nf = 0; nf < 4; ++nf)
                    s[qf][nf] = MFMA16(kf[nf], qfrag[qf][kk], s[qf][nf]);
        }
        __builtin_amdgcn_s_setprio(0);

        // softmax + in-register P fragments (fast path: m==0 -> p = exp2(s))
        short8 pa[2][2];
#pragma unroll
        for (int qf = 0; qf < 2; ++qf) {
            float a0 = fmaxf(fmaxf(s[qf][0][0], s[qf][0][1]), fmaxf(s[qf][0][2], s[qf][0][3]));
            float a1 = fmaxf(fmaxf(s[qf][1][0], s[qf][1][1]), fmaxf(s[qf][1][2], s[qf][1][3]));
            float a2 = fmaxf(fmaxf(s[qf][2][0], s[qf][2][1]), fmaxf(s[qf][2][2], s[qf][2][3]));
            float a3 = fmaxf(fmaxf(s[qf][3][0], s[qf][3][1]), fmaxf(s[qf][3][2], s[qf][3][3]));
            float lm = fmaxf(fmaxf(a0, a1), fmaxf(a2, a3));
            // rare path: tile max grew past bound -> true row max + rescale
            if (__any(lm - mrun[qf] > 8.f)) {
                float mr = lm;
                mr = fmaxf(mr, __shfl_xor(mr, 16));
                mr = fmaxf(mr, __shfl_xor(mr, 32));
                float mnew = fmaxf(mrun[qf], mr);
                float rs = __builtin_amdgcn_exp2f(mrun[qf] - mnew);
                mrun[qf] = mnew;
                lrun[qf] *= rs;
#pragma unroll
                for (int df = 0; df < 4; ++df)
#pragma unroll
                    for (int r = 0; r < 4; ++r) o[qf][df][r] *= rs;
            }
            float p[4][4];
            const float mq = mrun[qf];
            if (mq == 0.f) {
#pragma unroll
                for (int nf = 0; nf < 4; ++nf)
#pragma unroll
                    for (int r = 0; r < 4; ++r)
                        p[nf][r] = __builtin_amdgcn_exp2f(s[qf][nf][r]);
            } else {
#pragma unroll
                for (int nf = 0; nf < 4; ++nf)
#pragma unroll
                    for (int r = 0; r < 4; ++r)
                        p[nf][r] = __builtin_amdgcn_exp2f(s[qf][nf][r] - mq);
            }
            float t0 = (p[0][0] + p[0][1]) + (p[0][2] + p[0][3]);
            float t1 = (p[1][0] + p[1][1]) + (p[1][2] + p[1][3]);
            float t2 = (p[2][0] + p[2][1]) + (p[2][2] + p[2][3]);
            float t3 = (p[3][0] + p[3][1]) + (p[3][2] + p[3][3]);
            lrun[qf] += (t0 + t1) + (t2 + t3);
            union { uint4v u; short8 s8; } c0, c1;
            c0.u[0] = cvt_pk_bf16(p[0][0], p[0][1]);
            c0.u[1] = cvt_pk_bf16(p[0][2], p[0][3]);
            c0.u[2] = cvt_pk_bf16(p[2][0], p[2][1]);
            c0.u[3] = cvt_pk_bf16(p[2][2], p[2][3]);
            c1.u[0] = cvt_pk_bf16(p[1][0], p[1][1]);
            c1.u[1] = cvt_pk_bf16(p[1][2], p[1][3]);
            c1.u[2] = cvt_pk_bf16(p[3][0], p[3][1]);
            c1.u[3] = cvt_pk_bf16(p[3][2], p[3][3]);
            pa[qf][0] = c0.s8;
            pa[qf][1] = c1.s8;
        }

        // PV: o^T[d][q] += V^T-frag . P^T-frag (P^T straight from registers)
        __builtin_amdgcn_s_setprio(1);
#pragma unroll
        for (int kk = 0; kk < 2; ++kk)
#pragma unroll
            for (int df = 0; df < 4; ++df) {
                int r = df * 16 + l15;
                short8 vf = *(const short8*)(Vb_ + r * 128 + (((kk * 4 + grp) ^ (r & 7)) << 4));
#pragma unroll
                for (int qf = 0; qf < 2; ++qf)
                    o[qf][df] = MFMA16(vf, pa[qf][kk], o[qf][df]);
            }
        __builtin_amdgcn_s_setprio(0);
        if (kt < 15) __syncthreads();   // final iter: epilogue touches no LDS
    }
#undef STAGE

    // epilogue: l-reduce across grp groups, normalize, add residual q, store
#pragma unroll
    for (int qf = 0; qf < 2; ++qf) {
        float l = lrun[qf];
        l += __shfl_xor(l, 16);
        l += __shfl_xor(l, 32);
        float linv = 1.f / l;
        size_t row = (size_t)(b * 1024 + qbase + qf * 16 + l15);
#pragma unroll
        for (int df = 0; df < 4; ++df) {
            int col = h * 64 + df * 16 + grp * 4;
            ushort4v res = *(const ushort4v*)(qb + row * 512 + col);
            ushort4v outv;
#pragma unroll
            for (int r = 0; r < 4; ++r)
                outv[r] = f2bf(o[qf][df][r] * linv + bf2f(res[r]));
            *(ushort4v*)(Opre + row * 512 + col) = outv;
        }
    }
}

// ---------------------------------------------------------------------------
// Kernel 4/6: LayerNorm. OUT_F32=0 writes bf16 PRE-SWIZZLED (c^(row&7), for
// ffn A staging); OUT_F32=1 writes fp32 final output.
// ---------------------------------------------------------------------------
template <int OUT_F32>
__global__ __launch_bounds__(256) void ln_kernel(
    const unsigned short* in, const float* __restrict__ g, const float* __restrict__ be,
    unsigned short* outb, float* outf)
{
    const int wid = threadIdx.x >> 6, lane = threadIdx.x & 63;
    const size_t row = (size_t)blockIdx.x * 4 + wid;
    short8 v = *(const short8*)(in + row * 512 + lane * 8);
    float x[8];
    float sum = 0.f, sq = 0.f;
#pragma unroll
    for (int j = 0; j < 8; ++j) {
        x[j] = bf2f((unsigned short)v[j]);
        sum += x[j];
        sq += x[j] * x[j];
    }
#pragma unroll
    for (int ofs = 1; ofs < 64; ofs <<= 1) {
        sum += __shfl_xor(sum, ofs);
        sq += __shfl_xor(sq, ofs);
    }
    float mean = sum * (1.f / 512.f);
    float var = sq * (1.f / 512.f) - mean * mean;
    float rs = rsqrtf(var + 1e-5f);
    float4v g0 = *(const float4v*)(g + lane * 8);
    float4v g1 = *(const float4v*)(g + lane * 8 + 4);
    float4v b0 = *(const float4v*)(be + lane * 8);
    float4v b1 = *(const float4v*)(be + lane * 8 + 4);
    float y[8];
#pragma unroll
    for (int j = 0; j < 4; ++j) y[j] = (x[j] - mean) * rs * g0[j] + b0[j];
#pragma unroll
    for (int j = 0; j < 4; ++j) y[4 + j] = (x[4 + j] - mean) * rs * g1[j] + b1[j];
    if (OUT_F32) {
        float4v o0, o1;
#pragma unroll
        for (int j = 0; j < 4; ++j) { o0[j] = y[j]; o1[j] = y[4 + j]; }
        *(float4v*)(outf + row * 512 + lane * 8) = o0;
        *(float4v*)(outf + row * 512 + lane * 8 + 4) = o1;
    } else {
        short8 o;
#pragma unroll
        for (int j = 0; j < 8; ++j) o[j] = (short)f2bf(y[j]);
        size_t op = row * 512 + (size_t)((lane >> 3) * 64 + (((lane & 7) ^ ((int)row & 7)) * 8));
        *(short8*)(outb + op) = o;
    }
}

// ---------------------------------------------------------------------------
// Kernel 5: O2 = O1 + relu(O1 @ Wo + bo). 64x128 per 256-thread block
// (4 waves, wave tile 64x32, acc 32 VGPR), LDS 24KB, grid 1024 = 16 waves/CU.
// gl16 from pre-swizzled O1/WoT. XCD decode: 4 col-tiles per 64-row block.
// ---------------------------------------------------------------------------
__global__ __launch_bounds__(256) void ffn_kernel(
    const unsigned short* __restrict__ O1, const unsigned short* __restrict__ WoT,
    const float* __restrict__ bo, unsigned short* __restrict__ O2)
{
    __shared__ unsigned short Al[64 * 64];     // 8 KB
    __shared__ unsigned short Bl[128 * 64];    // 16 KB

    const int bid = blockIdx.x;
    const int xcd = bid & 7, idx = bid >> 3;
    const int rowbase = (xcd + 8 * (idx >> 2)) * 64;
    const int colbase = (idx & 3) * 128;

    const int t = threadIdx.x;
    const int lane = t & 63, wid = t >> 6;
    const int l15 = lane & 15, grp = lane >> 4;
    const int srow = t >> 3, sblk = t & 7;

    f32x4 acc[4][2];
#pragma unroll
    for (int i = 0; i < 4; ++i)
#pragma unroll
        for (int j = 0; j < 2; ++j) acc[i][j] = (f32x4){0.f, 0.f, 0.f, 0.f};

    for (int kt = 0; kt < 8; ++kt) {
#pragma unroll
        for (int p = 0; p < 2; ++p)
            gl16(O1 + (size_t)(rowbase + p * 32 + srow) * 512 + kt * 64 + sblk * 8,
                 &Al[p * 2048 + wid * 512]);
#pragma unroll
        for (int p = 0; p < 4; ++p)
            gl16(WoT + (size_t)(colbase + p * 32 + srow) * 512 + kt * 64 + sblk * 8,
                 &Bl[p * 2048 + wid * 512]);
        __syncthreads();
#pragma unroll
        for (int kk = 0; kk < 2; ++kk) {
            short8 af[4], bfr[2];
#pragma unroll
            for (int m = 0; m < 4; ++m) {
                int r = m * 16 + l15;
                af[m] = *(const short8*)((const char*)Al + r * 128 + (((kk * 4 + grp) ^ (r & 7)) << 4));
            }
#pragma unroll
            for (int n = 0; n < 2; ++n) {
                int r = wid * 32 + n * 16 + l15;
                bfr[n] = *(const short8*)((const char*)Bl + r * 128 + (((kk * 4 + grp) ^ (r & 7)) << 4));
            }
#pragma unroll
            for (int m = 0; m < 4; ++m)
#pragma unroll
                for (int n = 0; n < 2; ++n)
                    acc[m][n] = MFMA16(af[m], bfr[n], acc[m][n]);
        }
        __syncthreads();
    }
#pragma unroll
    for (int n = 0; n < 2; ++n) {
        int col = colbase + wid * 32 + n * 16 + l15;
        float bvv = bo[col];
#pragma unroll
        for (int m = 0; m < 4; ++m) {
            int row0 = rowbase + m * 16 + grp * 4;
#pragma unroll
            for (int r = 0; r < 4; ++r) {
                size_t row = (size_t)(row0 + r);
                float val = fmaxf(acc[m][n][r] + bvv, 0.f);
                float resid = bf2f(O1[row * 512 + (col ^ (((int)row & 7) << 3))]);
                O2[row * 512 + col] = f2bf(resid + val);
            }
        }
    }
}

// ---------------------------------------------------------------------------
extern "C" void kernel_launch(void* const* d_in, const int* in_sizes, int n_in,
                              void* d_out, int out_size, void* d_ws, size_t ws_size,
                              hipStream_t stream)
{
    const float* Q   = (const float*)d_in[0];
    const float* Kin = (const float*)d_in[1];
    const float* Wq  = (const float*)d_in[2];
    const float* bq  = (const float*)d_in[3];
    const float* Wk  = (const float*)d_in[4];
    const float* bk  = (const float*)d_in[5];
    const float* Wv  = (const float*)d_in[6];
    const float* bv  = (const float*)d_in[7];
    const float* Wo  = (const float*)d_in[8];
    const float* bo  = (const float*)d_in[9];
    const float* g0  = (const float*)d_in[10];
    const float* b0  = (const float*)d_in[11];
    const float* g1  = (const float*)d_in[12];
    const float* b1  = (const float*)d_in[13];
    float* out = (float*)d_out;

    unsigned short* ws = (unsigned short*)d_ws;
    const size_t WSZ = 512 * 512;
    const size_t BIG = 16384 * 512;
    unsigned short* WqT  = ws;
    unsigned short* WkT  = WqT + WSZ;
    unsigned short* WvT  = WkT + WSZ;
    unsigned short* WoT  = WvT + WSZ;
    unsigned short* qb   = WoT + WSZ;
    unsigned short* kb   = qb + BIG;
    unsigned short* vT   = kb + BIG;
    unsigned short* Opre = vT + BIG;
    unsigned short* O2   = Opre + BIG;
    unsigned short* O1   = Opre;   // LN0 in place

    wtrans_kernel<<<dim3(8, 8, 4), 256, 0, stream>>>(Wq, Wk, Wv, Wo, WqT, WkT, WvT, WoT);
    proj_kernel<<<dim3(1536), 512, 0, stream>>>(Q, Kin, WqT, WkT, WvT, bq, bk, bv, qb, kb, vT);
    attn_kernel<<<dim3(1024), 256, 0, stream>>>(qb, kb, vT, Opre);
    ln_kernel<0><<<dim3(4096), 256, 0, stream>>>(Opre, g0, b0, O1, nullptr);
    ffn_kernel<<<dim3(1024), 256, 0, stream>>>(O1, WoT, bo, O2);
    ln_kernel<1><<<dim3(4096), 256, 0, stream>>>(O2, g1, b1, nullptr, out);
}

// Round 18
// 128.626 us; speedup vs baseline: 1.0390x; 1.0390x over previous
//
#include <hip/hip_runtime.h>
#include <hip/hip_bf16.h>

typedef __attribute__((ext_vector_type(8))) short short8;
typedef __attribute__((ext_vector_type(4))) float f32x4;
typedef __attribute__((ext_vector_type(4))) float float4v;
typedef __attribute__((ext_vector_type(4))) unsigned short ushort4v;
typedef __attribute__((ext_vector_type(4))) unsigned int uint4v;

#define MFMA16(a, b, c) __builtin_amdgcn_mfma_f32_16x16x32_bf16((a), (b), (c), 0, 0, 0)

__device__ __forceinline__ unsigned short f2bf(float f) {
    union { float f; unsigned u; } v; v.f = f;
    unsigned r = v.u + 0x7fffu + ((v.u >> 16) & 1u);
    return (unsigned short)(r >> 16);
}
__device__ __forceinline__ float bf2f(unsigned short h) {
    union { unsigned u; float f; } v; v.u = (unsigned)h << 16;
    return v.f;
}
__device__ __forceinline__ float asf(unsigned u) {
    union { unsigned u; float f; } v; v.u = u;
    return v.f;
}
__device__ __forceinline__ unsigned cvt_pk_bf16(float lo, float hi) {
    unsigned r;
    asm("v_cvt_pk_bf16_f32 %0, %1, %2" : "=v"(r) : "v"(lo), "v"(hi));
    return r;
}
// async global->LDS, 16B per lane. LDS dest = wave-uniform base + lane*16.
__device__ __forceinline__ void gl16(const void* g, void* l) {
    __builtin_amdgcn_global_load_lds(
        (const __attribute__((address_space(1))) unsigned int*)g,
        (__attribute__((address_space(3))) unsigned int*)l, 16, 0, 0);
}

// ---------------------------------------------------------------------------
// Kernel 1: weights 512x512 fp32 -> bf16 transposed, PRE-SWIZZLED rows
// (chunk c of row n stored at c^(n&7)).
// ---------------------------------------------------------------------------
__global__ __launch_bounds__(256) void wtrans_kernel(
    const float* __restrict__ W0, const float* __restrict__ W1,
    const float* __restrict__ W2, const float* __restrict__ W3,
    unsigned short* __restrict__ T0, unsigned short* __restrict__ T1,
    unsigned short* __restrict__ T2, unsigned short* __restrict__ T3)
{
    const int z = blockIdx.z;
    const float* W = (z == 0) ? W0 : (z == 1) ? W1 : (z == 2) ? W2 : W3;
    unsigned short* T = (z == 0) ? T0 : (z == 1) ? T1 : (z == 2) ? T2 : T3;

    __shared__ unsigned short tile[64][72];
    const int k0 = blockIdx.x * 64, n0 = blockIdx.y * 64;
    const int t = threadIdx.x;

#pragma unroll
    for (int p = 0; p < 4; ++p) {
        int idx = p * 256 + t;
        int k = idx >> 4, c4 = idx & 15;
        float4v v = *(const float4v*)(W + (size_t)(k0 + k) * 512 + n0 + c4 * 4);
#pragma unroll
        for (int j = 0; j < 4; ++j) tile[k][c4 * 4 + j] = f2bf(v[j]);
    }
    __syncthreads();
#pragma unroll
    for (int p = 0; p < 2; ++p) {
        int idx = p * 256 + t;
        int n = idx >> 3, c = idx & 7;
        short8 o;
#pragma unroll
        for (int j = 0; j < 8; ++j) o[j] = (short)tile[c * 8 + j][n];
        *(short8*)(T + (size_t)(n0 + n) * 512 + k0 + ((c ^ (n & 7)) * 8)) = o;
    }
}

// ---------------------------------------------------------------------------
// Kernel 2: q/k/v projection GEMM (R14/R16 best form). 512 threads = 8 waves,
// TILE 128x256, BK=64, wave tile 64x64. B staged via gl16 from pre-swizzled
// WT (issued first); A staged raw fp32 via gl16 (pre-swizzled source,
// converted bf16 on read). LDS 64KB -> 2 blocks/CU. XCD-aware grid 768.
// Epilogues: z==0 -> qb plain; z==1 -> kb key-row-permuted (kappa^-1) +
// col-swizzled; z==2 -> vT transposed + pre-swizzled key-chunks.
// ---------------------------------------------------------------------------
__global__ __launch_bounds__(512) void proj_kernel(
    const float* __restrict__ Q, const float* __restrict__ Kin,
    const unsigned short* __restrict__ WqT, const unsigned short* __restrict__ WkT,
    const unsigned short* __restrict__ WvT,
    const float* __restrict__ bq, const float* __restrict__ bk, const float* __restrict__ bv,
    unsigned short* __restrict__ qb, unsigned short* __restrict__ kb,
    unsigned short* __restrict__ vT)
{
    const int bid = blockIdx.x;
    const int xcd = bid & 7, idx = bid >> 3;
    const int q6 = idx / 6, combo = idx - q6 * 6;
    const int z = combo >> 1;
    const int rowbase = (xcd + 8 * q6) * 128;
    const int colbase = (combo & 1) * 256;

    const float* A = (z == 0) ? Q : Kin;
    const unsigned short* WT = (z == 0) ? WqT : (z == 1) ? WkT : WvT;
    const float* bias = (z == 0) ? bq : (z == 1) ? bk : bv;

    __shared__ float Alf[128 * 64];            // 32 KB fp32, chunk-swizzled
    __shared__ unsigned short Bl[256 * 64];    // 32 KB bf16

    const int t = threadIdx.x;
    const int lane = t & 63, wid = t >> 6;
    const int wm = wid >> 2, wn = wid & 3;
    const int l15 = lane & 15, grp = lane >> 4;

    f32x4 acc[4][4];
#pragma unroll
    for (int i = 0; i < 4; ++i)
#pragma unroll
        for (int j = 0; j < 4; ++j) acc[i][j] = (f32x4){0.f, 0.f, 0.f, 0.f};

    for (int kt = 0; kt < 8; ++kt) {
        // B: 256 rows x 8 chunks, 4 gl16/thread, linear dest
#pragma unroll
        for (int j = 0; j < 4; ++j) {
            int n = wid * 32 + j * 8 + (lane >> 3);
            gl16(WT + (size_t)(colbase + n) * 512 + kt * 64 + (lane & 7) * 8,
                 &Bl[wid * 2048 + j * 512]);
        }
        // A: 128 rows x 16 chunks fp32, 4 gl16/thread, source pre-swizzled
#pragma unroll
        for (int i = 0; i < 4; ++i) {
            int r = wid * 16 + i * 4 + (lane >> 4);
            int cdst = lane & 15;
            gl16(A + (size_t)(rowbase + r) * 512 + kt * 64 + ((cdst ^ (r & 15)) << 2),
                 &Alf[wid * 1024 + i * 256]);
        }
        __syncthreads();
#pragma unroll
        for (int kk = 0; kk < 2; ++kk) {
            short8 af[4], bfr[4];
#pragma unroll
            for (int m = 0; m < 4; ++m) {
                int r = wm * 64 + m * 16 + l15;
                int c0 = kk * 8 + grp * 2;
                const char* base = (const char*)Alf + r * 256;
                float4v f0 = *(const float4v*)(base + ((c0 ^ (r & 15)) << 4));
                float4v f1 = *(const float4v*)(base + (((c0 + 1) ^ (r & 15)) << 4));
                union { uint4v u; short8 s8; } cv;
                cv.u[0] = cvt_pk_bf16(f0[0], f0[1]);
                cv.u[1] = cvt_pk_bf16(f0[2], f0[3]);
                cv.u[2] = cvt_pk_bf16(f1[0], f1[1]);
                cv.u[3] = cvt_pk_bf16(f1[2], f1[3]);
                af[m] = cv.s8;
            }
#pragma unroll
            for (int n = 0; n < 4; ++n) {
                int r = wn * 64 + n * 16 + l15;
                bfr[n] = *(const short8*)((const char*)Bl + r * 128 + (((kk * 4 + grp) ^ (r & 7)) << 4));
            }
#pragma unroll
            for (int m = 0; m < 4; ++m)
#pragma unroll
                for (int n = 0; n < 4; ++n)
                    acc[m][n] = MFMA16(af[m], bfr[n], acc[m][n]);
        }
        __syncthreads();
    }

    if (z == 2) {
        // v epilogue: write vT[(b*8+h)*64+d][key] transposed + pre-swizzled
#pragma unroll
        for (int n = 0; n < 4; ++n) {
            int col = colbase + wn * 64 + n * 16 + l15;
            float bvv = bias[col];
            int h_ = col >> 6, d_ = col & 63;
#pragma unroll
            for (int m = 0; m < 4; ++m) {
                int row0 = rowbase + wm * 64 + m * 16 + grp * 4;
                int b_ = row0 >> 10;
                int key0 = row0 & 1023;
                int keypos = (key0 & ~63) + ((((key0 >> 3) & 7) ^ (d_ & 7)) << 3) + (key0 & 7);
                ushort4v w;
#pragma unroll
                for (int r = 0; r < 4; ++r) w[r] = f2bf(acc[m][n][r] + bvv);
                *(ushort4v*)(vT + ((size_t)(b_ * 8 + h_) * 64 + d_) * 1024 + keypos) = w;
            }
        }
    } else if (z == 1) {
        // k epilogue: row-permute within 64-blocks (kappa^-1) + col swizzle by
        // stored row. kappa^-1(k): y = [k2, k5, k4, k3, k1, k0]
#pragma unroll
        for (int n = 0; n < 4; ++n) {
            int col = colbase + wn * 64 + n * 16 + l15;
            float bvv = bias[col];
#pragma unroll
            for (int m = 0; m < 4; ++m) {
                int row0 = rowbase + wm * 64 + m * 16 + grp * 4;
#pragma unroll
                for (int r = 0; r < 4; ++r) {
                    int row = row0 + r;
                    int k6 = row & 63;
                    int y = ((k6 & 4) << 3) | ((k6 & 56) >> 1) | (k6 & 3);
                    int Y = (row & ~63) | y;
                    int colp = col ^ ((y & 7) << 3);
                    kb[(size_t)Y * 512 + colp] = f2bf(acc[m][n][r] + bvv);
                }
            }
        }
    } else {
#pragma unroll
        for (int n = 0; n < 4; ++n) {
            int col = colbase + wn * 64 + n * 16 + l15;
            float bvv = bias[col];
#pragma unroll
            for (int m = 0; m < 4; ++m) {
                int row0 = rowbase + wm * 64 + m * 16 + grp * 4;
#pragma unroll
                for (int r = 0; r < 4; ++r)
                    qb[(size_t)(row0 + r) * 512 + col] = f2bf(acc[m][n][r] + bvv);
            }
        }
    }
}

// ---------------------------------------------------------------------------
// Kernel 3: flash attention (R5 structure + register-level wins). 256 threads
// = 4 waves x 32 q, Qwg=128, grid 1024. K/V double-buffered in 32KB LDS via
// gl16; one __syncthreads per iter (skipped on the final iter). P fully
// in-register via kb's key-row permutation; q pre-scaled by C. setprio kept
// (m191: positive on attn).
// ---------------------------------------------------------------------------
__global__ __launch_bounds__(256, 4) void attn_kernel(
    const unsigned short* __restrict__ qb, const unsigned short* __restrict__ kbs,
    const unsigned short* __restrict__ vTs, unsigned short* __restrict__ Opre)
{
    __shared__ unsigned short Kl[2][64 * 64];   // [key'][kd] swizzled, row-permuted
    __shared__ unsigned short Vl[2][64 * 64];   // [d][key] swizzled

    const int t = threadIdx.x, lane = t & 63, wid = t >> 6;
    const int l15 = lane & 15, grp = lane >> 4;

    // XCD-aware decode: bid&7 = h; qt-siblings of one (b,h) adjacent.
    const int bid = blockIdx.x;
    const int h = bid & 7, r2 = bid >> 3;
    const int b = r2 >> 3, qt = r2 & 7;
    const int qbase = qt * 128 + wid * 32;

    // staging source addrs (per-lane); dest = wave-uniform base + lane*16
    const unsigned short* ksrc = kbs + (size_t)(b * 1024 + (t >> 3)) * 512 + h * 64 + (t & 7) * 8;
    const unsigned short* vsrc = vTs + ((size_t)(b * 8 + h) * 64 + (t >> 3)) * 1024 + (t & 7) * 8;

#define STAGE(bsel, tile) do { \
    gl16(ksrc + (size_t)((tile) * 64) * 512,      &Kl[bsel][wid * 512]); \
    gl16(ksrc + (size_t)((tile) * 64 + 32) * 512, &Kl[bsel][2048 + wid * 512]); \
    gl16(vsrc + (tile) * 64,                      &Vl[bsel][wid * 512]); \
    gl16(vsrc + 32768 + (tile) * 64,              &Vl[bsel][2048 + wid * 512]); } while (0)

    const float C = 0.06375871f;  // (1/sqrt(512)) * log2(e)

    // Q as B-frags
    short8 qfrag[2][2];
#pragma unroll
    for (int qf = 0; qf < 2; ++qf)
#pragma unroll
        for (int kk = 0; kk < 2; ++kk)
            qfrag[qf][kk] = *(const short8*)(
                qb + (size_t)(b * 1024 + qbase + qf * 16 + l15) * 512 + h * 64 + kk * 32 + grp * 8);

    STAGE(0, 0);

    // pre-scale q by C in registers (one-time): s from MFMA comes pre-scaled
#pragma unroll
    for (int qf = 0; qf < 2; ++qf)
#pragma unroll
        for (int kk = 0; kk < 2; ++kk) {
            union { short8 s; uint4v u; } io;
            io.s = qfrag[qf][kk];
#pragma unroll
            for (int j = 0; j < 4; ++j) {
                unsigned w = io.u[j];
                float flo = asf(w << 16) * C;
                float fhi = asf(w & 0xffff0000u) * C;
                io.u[j] = cvt_pk_bf16(flo, fhi);
            }
            qfrag[qf][kk] = io.s;
        }

    f32x4 o[2][4];
#pragma unroll
    for (int qf = 0; qf < 2; ++qf)
#pragma unroll
        for (int df = 0; df < 4; ++df) o[qf][df] = (f32x4){0.f, 0.f, 0.f, 0.f};
    float mrun[2] = {0.f, 0.f}, lrun[2] = {0.f, 0.f};

    __syncthreads();

    for (int kt = 0; kt < 16; ++kt) {
        const int buf = kt & 1;
        if (kt < 15) STAGE(buf ^ 1, kt + 1);   // flies during compute

        const char* Kb_ = (const char*)&Kl[buf][0];
        const char* Vb_ = (const char*)&Vl[buf][0];

        // S^T rows rho = nf*16+grp*4+r (key kappa(rho)), col q = l15; PRE-SCALED
        f32x4 s[2][4];
#pragma unroll
        for (int qf = 0; qf < 2; ++qf)
#pragma unroll
            for (int nf = 0; nf < 4; ++nf) s[qf][nf] = (f32x4){0.f, 0.f, 0.f, 0.f};
        __builtin_amdgcn_s_setprio(1);
#pragma unroll
        for (int kk = 0; kk < 2; ++kk) {
            short8 kf[4];
#pragma unroll
            for (int nf = 0; nf < 4; ++nf) {
                int r = nf * 16 + l15;
                kf[nf] = *(const short8*)(Kb_ + r * 128 + (((kk * 4 + grp) ^ (r & 7)) << 4));
            }
#pragma unroll
            for (int qf = 0; qf < 2; ++qf)
#pragma unroll
                for (int nf = 0; nf < 4; ++nf)
                    s[qf][nf] = MFMA16(kf[nf], qfrag[qf][kk], s[qf][nf]);
        }
        __builtin_amdgcn_s_setprio(0);

        // softmax + in-register P fragments (fast path: m==0 -> p = exp2(s))
        short8 pa[2][2];
#pragma unroll
        for (int qf = 0; qf < 2; ++qf) {
            float a0 = fmaxf(fmaxf(s[qf][0][0], s[qf][0][1]), fmaxf(s[qf][0][2], s[qf][0][3]));
            float a1 = fmaxf(fmaxf(s[qf][1][0], s[qf][1][1]), fmaxf(s[qf][1][2], s[qf][1][3]));
            float a2 = fmaxf(fmaxf(s[qf][2][0], s[qf][2][1]), fmaxf(s[qf][2][2], s[qf][2][3]));
            float a3 = fmaxf(fmaxf(s[qf][3][0], s[qf][3][1]), fmaxf(s[qf][3][2], s[qf][3][3]));
            float lm = fmaxf(fmaxf(a0, a1), fmaxf(a2, a3));
            // rare path: tile max grew past bound -> true row max + rescale
            if (__any(lm - mrun[qf] > 8.f)) {
                float mr = lm;
                mr = fmaxf(mr, __shfl_xor(mr, 16));
                mr = fmaxf(mr, __shfl_xor(mr, 32));
                float mnew = fmaxf(mrun[qf], mr);
                float rs = __builtin_amdgcn_exp2f(mrun[qf] - mnew);
                mrun[qf] = mnew;
                lrun[qf] *= rs;
#pragma unroll
                for (int df = 0; df < 4; ++df)
#pragma unroll
                    for (int r = 0; r < 4; ++r) o[qf][df][r] *= rs;
            }
            float p[4][4];
            const float mq = mrun[qf];
            if (mq == 0.f) {
#pragma unroll
                for (int nf = 0; nf < 4; ++nf)
#pragma unroll
                    for (int r = 0; r < 4; ++r)
                        p[nf][r] = __builtin_amdgcn_exp2f(s[qf][nf][r]);
            } else {
#pragma unroll
                for (int nf = 0; nf < 4; ++nf)
#pragma unroll
                    for (int r = 0; r < 4; ++r)
                        p[nf][r] = __builtin_amdgcn_exp2f(s[qf][nf][r] - mq);
            }
            float t0 = (p[0][0] + p[0][1]) + (p[0][2] + p[0][3]);
            float t1 = (p[1][0] + p[1][1]) + (p[1][2] + p[1][3]);
            float t2 = (p[2][0] + p[2][1]) + (p[2][2] + p[2][3]);
            float t3 = (p[3][0] + p[3][1]) + (p[3][2] + p[3][3]);
            lrun[qf] += (t0 + t1) + (t2 + t3);
            union { uint4v u; short8 s8; } c0, c1;
            c0.u[0] = cvt_pk_bf16(p[0][0], p[0][1]);
            c0.u[1] = cvt_pk_bf16(p[0][2], p[0][3]);
            c0.u[2] = cvt_pk_bf16(p[2][0], p[2][1]);
            c0.u[3] = cvt_pk_bf16(p[2][2], p[2][3]);
            c1.u[0] = cvt_pk_bf16(p[1][0], p[1][1]);
            c1.u[1] = cvt_pk_bf16(p[1][2], p[1][3]);
            c1.u[2] = cvt_pk_bf16(p[3][0], p[3][1]);
            c1.u[3] = cvt_pk_bf16(p[3][2], p[3][3]);
            pa[qf][0] = c0.s8;
            pa[qf][1] = c1.s8;
        }

        // PV: o^T[d][q] += V^T-frag . P^T-frag (P^T straight from registers)
        __builtin_amdgcn_s_setprio(1);
#pragma unroll
        for (int kk = 0; kk < 2; ++kk)
#pragma unroll
            for (int df = 0; df < 4; ++df) {
                int r = df * 16 + l15;
                short8 vf = *(const short8*)(Vb_ + r * 128 + (((kk * 4 + grp) ^ (r & 7)) << 4));
#pragma unroll
                for (int qf = 0; qf < 2; ++qf)
                    o[qf][df] = MFMA16(vf, pa[qf][kk], o[qf][df]);
            }
        __builtin_amdgcn_s_setprio(0);
        if (kt < 15) __syncthreads();   // final iter: epilogue touches no LDS
    }
#undef STAGE

    // epilogue: l-reduce across grp groups, normalize, add residual q, store
#pragma unroll
    for (int qf = 0; qf < 2; ++qf) {
        float l = lrun[qf];
        l += __shfl_xor(l, 16);
        l += __shfl_xor(l, 32);
        float linv = 1.f / l;
        size_t row = (size_t)(b * 1024 + qbase + qf * 16 + l15);
#pragma unroll
        for (int df = 0; df < 4; ++df) {
            int col = h * 64 + df * 16 + grp * 4;
            ushort4v res = *(const ushort4v*)(qb + row * 512 + col);
            ushort4v outv;
#pragma unroll
            for (int r = 0; r < 4; ++r)
                outv[r] = f2bf(o[qf][df][r] * linv + bf2f(res[r]));
            *(ushort4v*)(Opre + row * 512 + col) = outv;
        }
    }
}

// ---------------------------------------------------------------------------
// Kernel 4/6: LayerNorm. OUT_F32=0 writes bf16 PRE-SWIZZLED (c^(row&7), for
// ffn A staging); OUT_F32=1 writes fp32 final output.
// ---------------------------------------------------------------------------
template <int OUT_F32>
__global__ __launch_bounds__(256) void ln_kernel(
    const unsigned short* in, const float* __restrict__ g, const float* __restrict__ be,
    unsigned short* outb, float* outf)
{
    const int wid = threadIdx.x >> 6, lane = threadIdx.x & 63;
    const size_t row = (size_t)blockIdx.x * 4 + wid;
    short8 v = *(const short8*)(in + row * 512 + lane * 8);
    float x[8];
    float sum = 0.f, sq = 0.f;
#pragma unroll
    for (int j = 0; j < 8; ++j) {
        x[j] = bf2f((unsigned short)v[j]);
        sum += x[j];
        sq += x[j] * x[j];
    }
#pragma unroll
    for (int ofs = 1; ofs < 64; ofs <<= 1) {
        sum += __shfl_xor(sum, ofs);
        sq += __shfl_xor(sq, ofs);
    }
    float mean = sum * (1.f / 512.f);
    float var = sq * (1.f / 512.f) - mean * mean;
    float rs = rsqrtf(var + 1e-5f);
    float4v g0 = *(const float4v*)(g + lane * 8);
    float4v g1 = *(const float4v*)(g + lane * 8 + 4);
    float4v b0 = *(const float4v*)(be + lane * 8);
    float4v b1 = *(const float4v*)(be + lane * 8 + 4);
    float y[8];
#pragma unroll
    for (int j = 0; j < 4; ++j) y[j] = (x[j] - mean) * rs * g0[j] + b0[j];
#pragma unroll
    for (int j = 0; j < 4; ++j) y[4 + j] = (x[4 + j] - mean) * rs * g1[j] + b1[j];
    if (OUT_F32) {
        float4v o0, o1;
#pragma unroll
        for (int j = 0; j < 4; ++j) { o0[j] = y[j]; o1[j] = y[4 + j]; }
        *(float4v*)(outf + row * 512 + lane * 8) = o0;
        *(float4v*)(outf + row * 512 + lane * 8 + 4) = o1;
    } else {
        short8 o;
#pragma unroll
        for (int j = 0; j < 8; ++j) o[j] = (short)f2bf(y[j]);
        size_t op = row * 512 + (size_t)((lane >> 3) * 64 + (((lane & 7) ^ ((int)row & 7)) * 8));
        *(short8*)(outb + op) = o;
    }
}

// ---------------------------------------------------------------------------
// Kernel 5: O2 = O1 + relu(O1 @ Wo + bo). 64x128 per 256-thread block
// (4 waves, wave tile 64x32, acc 32 VGPR), LDS 24KB, grid 1024 = 16 waves/CU.
// gl16 from pre-swizzled O1/WoT. XCD decode: 4 col-tiles per 64-row block.
// ---------------------------------------------------------------------------
__global__ __launch_bounds__(256) void ffn_kernel(
    const unsigned short* __restrict__ O1, const unsigned short* __restrict__ WoT,
    const float* __restrict__ bo, unsigned short* __restrict__ O2)
{
    __shared__ unsigned short Al[64 * 64];     // 8 KB
    __shared__ unsigned short Bl[128 * 64];    // 16 KB

    const int bid = blockIdx.x;
    const int xcd = bid & 7, idx = bid >> 3;
    const int rowbase = (xcd + 8 * (idx >> 2)) * 64;
    const int colbase = (idx & 3) * 128;

    const int t = threadIdx.x;
    const int lane = t & 63, wid = t >> 6;
    const int l15 = lane & 15, grp = lane >> 4;
    const int srow = t >> 3, sblk = t & 7;

    f32x4 acc[4][2];
#pragma unroll
    for (int i = 0; i < 4; ++i)
#pragma unroll
        for (int j = 0; j < 2; ++j) acc[i][j] = (f32x4){0.f, 0.f, 0.f, 0.f};

    for (int kt = 0; kt < 8; ++kt) {
#pragma unroll
        for (int p = 0; p < 2; ++p)
            gl16(O1 + (size_t)(rowbase + p * 32 + srow) * 512 + kt * 64 + sblk * 8,
                 &Al[p * 2048 + wid * 512]);
#pragma unroll
        for (int p = 0; p < 4; ++p)
            gl16(WoT + (size_t)(colbase + p * 32 + srow) * 512 + kt * 64 + sblk * 8,
                 &Bl[p * 2048 + wid * 512]);
        __syncthreads();
#pragma unroll
        for (int kk = 0; kk < 2; ++kk) {
            short8 af[4], bfr[2];
#pragma unroll
            for (int m = 0; m < 4; ++m) {
                int r = m * 16 + l15;
                af[m] = *(const short8*)((const char*)Al + r * 128 + (((kk * 4 + grp) ^ (r & 7)) << 4));
            }
#pragma unroll
            for (int n = 0; n < 2; ++n) {
                int r = wid * 32 + n * 16 + l15;
                bfr[n] = *(const short8*)((const char*)Bl + r * 128 + (((kk * 4 + grp) ^ (r & 7)) << 4));
            }
#pragma unroll
            for (int m = 0; m < 4; ++m)
#pragma unroll
                for (int n = 0; n < 2; ++n)
                    acc[m][n] = MFMA16(af[m], bfr[n], acc[m][n]);
        }
        __syncthreads();
    }
#pragma unroll
    for (int n = 0; n < 2; ++n) {
        int col = colbase + wid * 32 + n * 16 + l15;
        float bvv = bo[col];
#pragma unroll
        for (int m = 0; m < 4; ++m) {
            int row0 = rowbase + m * 16 + grp * 4;
#pragma unroll
            for (int r = 0; r < 4; ++r) {
                size_t row = (size_t)(row0 + r);
                float val = fmaxf(acc[m][n][r] + bvv, 0.f);
                float resid = bf2f(O1[row * 512 + (col ^ (((int)row & 7) << 3))]);
                O2[row * 512 + col] = f2bf(resid + val);
            }
        }
    }
}

// ---------------------------------------------------------------------------
extern "C" void kernel_launch(void* const* d_in, const int* in_sizes, int n_in,
                              void* d_out, int out_size, void* d_ws, size_t ws_size,
                              hipStream_t stream)
{
    const float* Q   = (const float*)d_in[0];
    const float* Kin = (const float*)d_in[1];
    const float* Wq  = (const float*)d_in[2];
    const float* bq  = (const float*)d_in[3];
    const float* Wk  = (const float*)d_in[4];
    const float* bk  = (const float*)d_in[5];
    const float* Wv  = (const float*)d_in[6];
    const float* bv  = (const float*)d_in[7];
    const float* Wo  = (const float*)d_in[8];
    const float* bo  = (const float*)d_in[9];
    const float* g0  = (const float*)d_in[10];
    const float* b0  = (const float*)d_in[11];
    const float* g1  = (const float*)d_in[12];
    const float* b1  = (const float*)d_in[13];
    float* out = (float*)d_out;

    unsigned short* ws = (unsigned short*)d_ws;
    const size_t WSZ = 512 * 512;
    const size_t BIG = 16384 * 512;
    unsigned short* WqT  = ws;
    unsigned short* WkT  = WqT + WSZ;
    unsigned short* WvT  = WkT + WSZ;
    unsigned short* WoT  = WvT + WSZ;
    unsigned short* qb   = WoT + WSZ;
    unsigned short* kb   = qb + BIG;
    unsigned short* vT   = kb + BIG;
    unsigned short* Opre = vT + BIG;
    unsigned short* O2   = Opre + BIG;
    unsigned short* O1   = Opre;   // LN0 in place

    wtrans_kernel<<<dim3(8, 8, 4), 256, 0, stream>>>(Wq, Wk, Wv, Wo, WqT, WkT, WvT, WoT);
    proj_kernel<<<dim3(768), 512, 0, stream>>>(Q, Kin, WqT, WkT, WvT, bq, bk, bv, qb, kb, vT);
    attn_kernel<<<dim3(1024), 256, 0, stream>>>(qb, kb, vT, Opre);
    ln_kernel<0><<<dim3(4096), 256, 0, stream>>>(Opre, g0, b0, O1, nullptr);
    ffn_kernel<<<dim3(1024), 256, 0, stream>>>(O1, WoT, bo, O2);
    ln_kernel<1><<<dim3(4096), 256, 0, stream>>>(O2, g1, b1, nullptr, out);
}